// Round 1
// baseline (931.515 us; speedup 1.0000x reference)
//
#include <hip/hip_runtime.h>

#define NG 512
#define HID 64

__global__ void deg_kernel(const int* __restrict__ dst, int* __restrict__ deg, int E) {
    int e = blockIdx.x * blockDim.x + threadIdx.x;
    if (e < E) atomicAdd(&deg[dst[e]], 1);
}

__global__ void dinv_kernel(const int* __restrict__ deg, float* __restrict__ dinv, int N) {
    int i = blockIdx.x * blockDim.x + threadIdx.x;
    if (i < N) dinv[i] = rsqrtf((float)deg[i] + 1.0f);
}

// h[i,j] = x[i,0]*W1[0,j] + x[i,1]*W1[1,j]   (x: [N,2], W1: [2,64])
__global__ void transform1_kernel(const float* __restrict__ x, const float* __restrict__ W1,
                                  float* __restrict__ h, int N) {
    int idx = blockIdx.x * blockDim.x + threadIdx.x;
    if (idx >= N * HID) return;
    int i = idx >> 6, j = idx & 63;
    h[idx] = fmaf(x[2 * i], W1[j], x[2 * i + 1] * W1[HID + j]);
}

// one 64-lane wave per edge; lane j handles feature j
__global__ void scatter_kernel(const int* __restrict__ src, const int* __restrict__ dst,
                               const float* __restrict__ dinv, const float* __restrict__ h,
                               float* __restrict__ agg, int E) {
    int t = blockIdx.x * blockDim.x + threadIdx.x;
    int e = t >> 6;
    int j = t & 63;
    if (e >= E) return;
    int s = src[e], d = dst[e];
    float norm = dinv[s] * dinv[d];
    atomicAdd(&agg[(size_t)d * HID + j], h[(size_t)s * HID + j] * norm);
}

// agg = relu(agg + h*dinv^2 + b)
__global__ void finish_kernel(const float* __restrict__ h, const float* __restrict__ dinv,
                              const float* __restrict__ b, float* __restrict__ agg, int N) {
    int idx = blockIdx.x * blockDim.x + threadIdx.x;
    if (idx >= N * HID) return;
    int i = idx >> 6, j = idx & 63;
    float di = dinv[i];
    float v = agg[idx] + h[idx] * di * di + b[j];
    agg[idx] = fmaxf(v, 0.0f);
}

// hout = hin @ W  (W: [64,64] staged in LDS; 4 nodes per 256-thread block)
__global__ __launch_bounds__(256) void transform2_kernel(const float* __restrict__ hin,
                                                         const float* __restrict__ W,
                                                         float* __restrict__ hout, int N) {
    __shared__ float Ws[HID * HID];
    __shared__ float hs[4 * HID];
    for (int t = threadIdx.x; t < HID * HID; t += 256) Ws[t] = W[t];
    int ln = threadIdx.x >> 6;
    int j  = threadIdx.x & 63;
    int i  = blockIdx.x * 4 + ln;
    if (i < N) hs[ln * HID + j] = hin[(size_t)i * HID + j];
    __syncthreads();
    if (i >= N) return;
    float acc = 0.0f;
#pragma unroll
    for (int k = 0; k < HID; ++k)
        acc = fmaf(hs[ln * HID + k], Ws[k * HID + j], acc);
    hout[(size_t)i * HID + j] = acc;
}

__global__ void pool_kernel(const float* __restrict__ h, const int* __restrict__ batch,
                            float* __restrict__ gsum, int* __restrict__ gcnt, int N) {
    int idx = blockIdx.x * blockDim.x + threadIdx.x;
    if (idx >= N * HID) return;
    int i = idx >> 6, j = idx & 63;
    int b = batch[i];
    atomicAdd(&gsum[b * HID + j], h[idx]);
    if (j == 0) atomicAdd(&gcnt[b], 1);
}

// per-graph: g = gsum/cnt; t = relu(g@Wf1+bf1); out = t@Wf2+bf2
__global__ void head_kernel(const float* __restrict__ gsum, const int* __restrict__ gcnt,
                            const float* __restrict__ Wf1, const float* __restrict__ bf1,
                            const float* __restrict__ Wf2, const float* __restrict__ bf2,
                            float* __restrict__ out) {
    __shared__ float gs[HID];
    __shared__ float ts[HID];
    int b = blockIdx.x;
    int j = threadIdx.x;
    float cnt = fmaxf((float)gcnt[b], 1.0f);
    gs[j] = gsum[b * HID + j] / cnt;
    __syncthreads();
    float acc = bf1[j];
#pragma unroll
    for (int k = 0; k < HID; ++k) acc = fmaf(gs[k], Wf1[k * HID + j], acc);
    ts[j] = fmaxf(acc, 0.0f);
    __syncthreads();
    if (j < 4) {
        float o = bf2[j];
#pragma unroll
        for (int k = 0; k < HID; ++k) o = fmaf(ts[k], Wf2[k * 4 + j], o);
        out[b * 4 + j] = o;
    }
}

extern "C" void kernel_launch(void* const* d_in, const int* in_sizes, int n_in,
                              void* d_out, int out_size, void* d_ws, size_t ws_size,
                              hipStream_t stream) {
    const float* x   = (const float*)d_in[0];
    const int*   ei  = (const int*)d_in[1];
    const int*   bat = (const int*)d_in[2];
    // d_in[3] = num_graphs scalar (512, fixed by problem)
    const float* W1  = (const float*)d_in[4];
    const float* b1  = (const float*)d_in[5];
    const float* W2  = (const float*)d_in[6];
    const float* b2  = (const float*)d_in[7];
    const float* Wf1 = (const float*)d_in[8];
    const float* bf1 = (const float*)d_in[9];
    const float* Wf2 = (const float*)d_in[10];
    const float* bf2 = (const float*)d_in[11];
    float* out = (float*)d_out;

    int N = in_sizes[2];
    int E = in_sizes[1] / 2;
    const int* src = ei;
    const int* dst = ei + E;

    char* ws = (char*)d_ws;
    size_t off = 0;
    auto alloc = [&](size_t bytes) {
        char* p = ws + off;
        off = (off + bytes + 255) & ~(size_t)255;
        return p;
    };
    int*   deg  = (int*)alloc((size_t)N * 4);
    float* dinv = (float*)alloc((size_t)N * 4);
    float* bufA = (float*)alloc((size_t)N * HID * 4);
    float* bufB = (float*)alloc((size_t)N * HID * 4);
    float* gsum = (float*)alloc((size_t)NG * HID * 4);
    int*   gcnt = (int*)alloc((size_t)NG * 4);

    size_t hbytes = (size_t)N * HID * 4;
    hipMemsetAsync(deg, 0, (size_t)N * 4, stream);
    hipMemsetAsync(bufB, 0, hbytes, stream);
    hipMemsetAsync(gsum, 0, (size_t)NG * HID * 4, stream);
    hipMemsetAsync(gcnt, 0, (size_t)NG * 4, stream);

    int nh = N * HID;
    deg_kernel<<<(E + 255) / 256, 256, 0, stream>>>(dst, deg, E);
    dinv_kernel<<<(N + 255) / 256, 256, 0, stream>>>(deg, dinv, N);

    // ---- layer 1: bufA = x@W1; bufB = relu(scatter + self + b1) -> h1
    transform1_kernel<<<(nh + 255) / 256, 256, 0, stream>>>(x, W1, bufA, N);
    scatter_kernel<<<(E * HID + 255) / 256, 256, 0, stream>>>(src, dst, dinv, bufA, bufB, E);
    finish_kernel<<<(nh + 255) / 256, 256, 0, stream>>>(bufA, dinv, b1, bufB, N);

    // ---- layer 2: bufA = h1@W2; zero bufB; scatter; finish -> h2 in bufB
    transform2_kernel<<<(N + 3) / 4, 256, 0, stream>>>(bufB, W2, bufA, N);
    hipMemsetAsync(bufB, 0, hbytes, stream);
    scatter_kernel<<<(E * HID + 255) / 256, 256, 0, stream>>>(src, dst, dinv, bufA, bufB, E);
    finish_kernel<<<(nh + 255) / 256, 256, 0, stream>>>(bufA, dinv, b2, bufB, N);

    // ---- pool + head
    pool_kernel<<<(nh + 255) / 256, 256, 0, stream>>>(bufB, bat, gsum, gcnt, N);
    head_kernel<<<NG, HID, 0, stream>>>(gsum, gcnt, Wf1, bf1, Wf2, bf2, out);
}

// Round 2
// 677.864 us; speedup vs baseline: 1.3742x; 1.3742x over previous
//
#include <hip/hip_runtime.h>

#define NG 512
#define HID 64

// ---------- degree & normalization ----------
__global__ void deg_kernel(const int* __restrict__ dst, int* __restrict__ deg, int E) {
    int e = blockIdx.x * blockDim.x + threadIdx.x;
    if (e < E) atomicAdd(&deg[dst[e]], 1);
}

__global__ void dinv_kernel(const int* __restrict__ deg, float* __restrict__ dinv, int N) {
    int i = blockIdx.x * blockDim.x + threadIdx.x;
    if (i < N) dinv[i] = rsqrtf((float)deg[i] + 1.0f);
}

// ---------- CSR build: block sums -> serial block scan -> in-block scan ----------
__global__ void block_sums_kernel(const int* __restrict__ deg, int* __restrict__ bsum, int N) {
    __shared__ int s[256];
    int i = blockIdx.x * 256 + threadIdx.x;
    s[threadIdx.x] = (i < N) ? deg[i] : 0;
    __syncthreads();
    for (int off = 128; off > 0; off >>= 1) {
        if (threadIdx.x < off) s[threadIdx.x] += s[threadIdx.x + off];
        __syncthreads();
    }
    if (threadIdx.x == 0) bsum[blockIdx.x] = s[0];
}

__global__ void scan_bsum_kernel(const int* __restrict__ bsum, int* __restrict__ bofs, int nb) {
    if (blockIdx.x == 0 && threadIdx.x == 0) {
        int acc = 0;
        for (int b = 0; b < nb; ++b) { bofs[b] = acc; acc += bsum[b]; }
    }
}

__global__ void scan_block_kernel(const int* __restrict__ deg, const int* __restrict__ bofs,
                                  int* __restrict__ rowptr, int N, int E) {
    __shared__ int tmp[256];
    int i = blockIdx.x * 256 + threadIdx.x;
    int v = (i < N) ? deg[i] : 0;
    tmp[threadIdx.x] = v;
    __syncthreads();
    for (int off = 1; off < 256; off <<= 1) {
        int t = (threadIdx.x >= off) ? tmp[threadIdx.x - off] : 0;
        __syncthreads();
        tmp[threadIdx.x] += t;
        __syncthreads();
    }
    if (i < N) rowptr[i] = bofs[blockIdx.x] + tmp[threadIdx.x] - v;  // exclusive
    if (i == 0) rowptr[N] = E;
}

__global__ void bucket_kernel(const int* __restrict__ src, const int* __restrict__ dst,
                              const int* __restrict__ rowptr, int* __restrict__ cur,
                              int* __restrict__ esrc, int E) {
    int e = blockIdx.x * blockDim.x + threadIdx.x;
    if (e >= E) return;
    int d = dst[e];
    int p = rowptr[d] + atomicAdd(&cur[d], 1);
    esrc[p] = src[e];
}

// ---------- dense transforms ----------
// h[i,j] = x[i,0]*W1[0,j] + x[i,1]*W1[1,j]
__global__ void transform1_kernel(const float* __restrict__ x, const float* __restrict__ W1,
                                  float* __restrict__ h, int N) {
    int idx = blockIdx.x * blockDim.x + threadIdx.x;
    if (idx >= N * HID) return;
    int i = idx >> 6, j = idx & 63;
    h[idx] = fmaf(x[2 * i], W1[j], x[2 * i + 1] * W1[HID + j]);
}

// hout = hin @ W  (W staged in LDS; 4 nodes / 256-thread block)
__global__ __launch_bounds__(256) void transform2_kernel(const float* __restrict__ hin,
                                                         const float* __restrict__ W,
                                                         float* __restrict__ hout, int N) {
    __shared__ float Ws[HID * HID];
    __shared__ float hs[4 * HID];
    for (int t = threadIdx.x; t < HID * HID; t += 256) Ws[t] = W[t];
    int ln = threadIdx.x >> 6;
    int j  = threadIdx.x & 63;
    int i  = blockIdx.x * 4 + ln;
    if (i < N) hs[ln * HID + j] = hin[(size_t)i * HID + j];
    __syncthreads();
    if (i >= N) return;
    float acc = 0.0f;
#pragma unroll
    for (int k = 0; k < HID; ++k)
        acc = fmaf(hs[ln * HID + k], Ws[k * HID + j], acc);
    hout[(size_t)i * HID + j] = acc;
}

// ---------- CSR gather aggregation (one wave per node, lane = feature) ----------
// out[d] = relu( dinv[d] * sum_{s in N(d)} h[s]*dinv[s]  +  h[d]*dinv[d]^2 + b )
__global__ void gather_kernel(const int* __restrict__ rowptr, const int* __restrict__ esrc,
                              const float* __restrict__ dinv, const float* __restrict__ h,
                              const float* __restrict__ b, float* __restrict__ out, int N) {
    int t = blockIdx.x * blockDim.x + threadIdx.x;
    int node = t >> 6, j = t & 63;
    if (node >= N) return;
    int k0 = rowptr[node], k1 = rowptr[node + 1];
    float acc = 0.0f;
    for (int k = k0; k < k1; ++k) {
        int s = esrc[k];
        acc = fmaf(h[(size_t)s * HID + j], dinv[s], acc);
    }
    float di = dinv[node];
    float v = fmaf(acc, di, fmaf(h[(size_t)node * HID + j], di * di, b[j]));
    out[(size_t)node * HID + j] = fmaxf(v, 0.0f);
}

// same, but epilogue pools straight into per-graph sums (h2 never materialized)
__global__ void gather_pool_kernel(const int* __restrict__ rowptr, const int* __restrict__ esrc,
                                   const float* __restrict__ dinv, const float* __restrict__ h,
                                   const float* __restrict__ b, const int* __restrict__ batch,
                                   float* __restrict__ gsum, int* __restrict__ gcnt, int N) {
    int t = blockIdx.x * blockDim.x + threadIdx.x;
    int node = t >> 6, j = t & 63;
    if (node >= N) return;
    int k0 = rowptr[node], k1 = rowptr[node + 1];
    float acc = 0.0f;
    for (int k = k0; k < k1; ++k) {
        int s = esrc[k];
        acc = fmaf(h[(size_t)s * HID + j], dinv[s], acc);
    }
    float di = dinv[node];
    float v = fmaf(acc, di, fmaf(h[(size_t)node * HID + j], di * di, b[j]));
    v = fmaxf(v, 0.0f);
    int g = batch[node];
    atomicAdd(&gsum[g * HID + j], v);
    if (j == 0) atomicAdd(&gcnt[g], 1);
}

// ---------- head: per-graph mean + 2-layer MLP ----------
__global__ void head_kernel(const float* __restrict__ gsum, const int* __restrict__ gcnt,
                            const float* __restrict__ Wf1, const float* __restrict__ bf1,
                            const float* __restrict__ Wf2, const float* __restrict__ bf2,
                            float* __restrict__ out) {
    __shared__ float gs[HID];
    __shared__ float ts[HID];
    int b = blockIdx.x;
    int j = threadIdx.x;
    float cnt = fmaxf((float)gcnt[b], 1.0f);
    gs[j] = gsum[b * HID + j] / cnt;
    __syncthreads();
    float acc = bf1[j];
#pragma unroll
    for (int k = 0; k < HID; ++k) acc = fmaf(gs[k], Wf1[k * HID + j], acc);
    ts[j] = fmaxf(acc, 0.0f);
    __syncthreads();
    if (j < 4) {
        float o = bf2[j];
#pragma unroll
        for (int k = 0; k < HID; ++k) o = fmaf(ts[k], Wf2[k * 4 + j], o);
        out[b * 4 + j] = o;
    }
}

extern "C" void kernel_launch(void* const* d_in, const int* in_sizes, int n_in,
                              void* d_out, int out_size, void* d_ws, size_t ws_size,
                              hipStream_t stream) {
    const float* x   = (const float*)d_in[0];
    const int*   ei  = (const int*)d_in[1];
    const int*   bat = (const int*)d_in[2];
    const float* W1  = (const float*)d_in[4];
    const float* b1  = (const float*)d_in[5];
    const float* W2  = (const float*)d_in[6];
    const float* b2  = (const float*)d_in[7];
    const float* Wf1 = (const float*)d_in[8];
    const float* bf1 = (const float*)d_in[9];
    const float* Wf2 = (const float*)d_in[10];
    const float* bf2 = (const float*)d_in[11];
    float* out = (float*)d_out;

    int N = in_sizes[2];
    int E = in_sizes[1] / 2;
    const int* src = ei;
    const int* dst = ei + E;
    int nb = (N + 255) / 256;

    char* ws = (char*)d_ws;
    size_t off = 0;
    auto alloc = [&](size_t bytes) {
        char* p = ws + off;
        off = (off + bytes + 255) & ~(size_t)255;
        return p;
    };
    int*   deg    = (int*)alloc((size_t)N * 4);
    float* dinv   = (float*)alloc((size_t)N * 4);
    int*   rowptr = (int*)alloc((size_t)(N + 1) * 4);
    int*   cur    = (int*)alloc((size_t)N * 4);
    int*   bsum   = (int*)alloc((size_t)nb * 4);
    int*   bofs   = (int*)alloc((size_t)nb * 4);
    int*   esrc   = (int*)alloc((size_t)E * 4);
    float* bufA   = (float*)alloc((size_t)N * HID * 4);
    float* bufB   = (float*)alloc((size_t)N * HID * 4);
    float* gsum   = (float*)alloc((size_t)NG * HID * 4);
    int*   gcnt   = (int*)alloc((size_t)NG * 4);

    hipMemsetAsync(deg, 0, (size_t)N * 4, stream);
    hipMemsetAsync(cur, 0, (size_t)N * 4, stream);
    hipMemsetAsync(gsum, 0, (size_t)NG * HID * 4, stream);
    hipMemsetAsync(gcnt, 0, (size_t)NG * 4, stream);

    int nh = N * HID;

    // degrees + normalization
    deg_kernel<<<(E + 255) / 256, 256, 0, stream>>>(dst, deg, E);
    dinv_kernel<<<(N + 255) / 256, 256, 0, stream>>>(deg, dinv, N);

    // CSR build (by dst)
    block_sums_kernel<<<nb, 256, 0, stream>>>(deg, bsum, N);
    scan_bsum_kernel<<<1, 64, 0, stream>>>(bsum, bofs, nb);
    scan_block_kernel<<<nb, 256, 0, stream>>>(deg, bofs, rowptr, N, E);
    bucket_kernel<<<(E + 255) / 256, 256, 0, stream>>>(src, dst, rowptr, cur, esrc, E);

    // layer 1: bufA = x@W1 ; bufB = relu(gather + self + b1)
    transform1_kernel<<<(nh + 255) / 256, 256, 0, stream>>>(x, W1, bufA, N);
    gather_kernel<<<(nh + 255) / 256, 256, 0, stream>>>(rowptr, esrc, dinv, bufA, b1, bufB, N);

    // layer 2: bufA = h1@W2 ; gather fused with mean-pool accumulation
    transform2_kernel<<<(N + 3) / 4, 256, 0, stream>>>(bufB, W2, bufA, N);
    gather_pool_kernel<<<(nh + 255) / 256, 256, 0, stream>>>(rowptr, esrc, dinv, bufA, b2, bat,
                                                            gsum, gcnt, N);

    // head
    head_kernel<<<NG, HID, 0, stream>>>(gsum, gcnt, Wf1, bf1, Wf2, bf2, out);
}

// Round 3
// 525.823 us; speedup vs baseline: 1.7715x; 1.2891x over previous
//
#include <hip/hip_runtime.h>

#define NG 512
#define HID 64

__device__ __forceinline__ float bcast_f(float v, int k) {
    return __int_as_float(__builtin_amdgcn_readlane(__float_as_int(v), k));
}

// ---------- degree & normalization ----------
__global__ void deg_kernel(const int* __restrict__ dst, int* __restrict__ deg, int E) {
    int e = blockIdx.x * blockDim.x + threadIdx.x;
    if (e < E) atomicAdd(&deg[dst[e]], 1);
}

__global__ void dinv_kernel(const int* __restrict__ deg, float* __restrict__ dinv, int N) {
    int i = blockIdx.x * blockDim.x + threadIdx.x;
    if (i < N) dinv[i] = rsqrtf((float)deg[i] + 1.0f);
}

// ---------- CSR build ----------
__global__ void block_sums_kernel(const int* __restrict__ deg, int* __restrict__ bsum, int N) {
    __shared__ int s[256];
    int i = blockIdx.x * 256 + threadIdx.x;
    s[threadIdx.x] = (i < N) ? deg[i] : 0;
    __syncthreads();
    for (int off = 128; off > 0; off >>= 1) {
        if (threadIdx.x < off) s[threadIdx.x] += s[threadIdx.x + off];
        __syncthreads();
    }
    if (threadIdx.x == 0) bsum[blockIdx.x] = s[0];
}

__global__ void scan_bsum_kernel(const int* __restrict__ bsum, int* __restrict__ bofs, int nb) {
    if (blockIdx.x == 0 && threadIdx.x == 0) {
        int acc = 0;
        for (int b = 0; b < nb; ++b) { bofs[b] = acc; acc += bsum[b]; }
    }
}

__global__ void scan_block_kernel(const int* __restrict__ deg, const int* __restrict__ bofs,
                                  int* __restrict__ rowptr, int N, int E) {
    __shared__ int tmp[256];
    int i = blockIdx.x * 256 + threadIdx.x;
    int v = (i < N) ? deg[i] : 0;
    tmp[threadIdx.x] = v;
    __syncthreads();
    for (int off = 1; off < 256; off <<= 1) {
        int t = (threadIdx.x >= off) ? tmp[threadIdx.x - off] : 0;
        __syncthreads();
        tmp[threadIdx.x] += t;
        __syncthreads();
    }
    if (i < N) rowptr[i] = bofs[blockIdx.x] + tmp[threadIdx.x] - v;  // exclusive
    if (i == 0) rowptr[N] = E;
}

__global__ void bucket_kernel(const int* __restrict__ src, const int* __restrict__ dst,
                              const int* __restrict__ rowptr, int* __restrict__ cur,
                              int* __restrict__ esrc, int E) {
    int e = blockIdx.x * blockDim.x + threadIdx.x;
    if (e >= E) return;
    int d = dst[e];
    int p = rowptr[d] + atomicAdd(&cur[d], 1);
    esrc[p] = src[e];
}

// ---------- layer 1 fused: h1 = relu( (Ax)@W1 + b1 ), x is [N,2] ----------
// one wave per node; lane-per-edge parallel gather of x (8B) -> butterfly reduce
__global__ void layer1_kernel(const float* __restrict__ x, const int* __restrict__ rowptr,
                              const int* __restrict__ esrc, const float* __restrict__ dinv,
                              const float* __restrict__ W1, const float* __restrict__ b1,
                              float* __restrict__ h1, int N) {
    int t = blockIdx.x * blockDim.x + threadIdx.x;
    int node = t >> 6, lane = t & 63;
    if (node >= N) return;
    const float2* x2 = (const float2*)x;
    int k0 = rowptr[node], k1 = rowptr[node + 1];
    float s0 = 0.0f, s1 = 0.0f;
    for (int base = k0; base < k1; base += 64) {
        int cnt = min(64, k1 - base);
        if (lane < cnt) {
            int s = esrc[base + lane];
            float dv = dinv[s];
            float2 xv = x2[s];
            s0 = fmaf(xv.x, dv, s0);
            s1 = fmaf(xv.y, dv, s1);
        }
    }
#pragma unroll
    for (int m = 32; m > 0; m >>= 1) {
        s0 += __shfl_xor(s0, m);
        s1 += __shfl_xor(s1, m);
    }
    float di = dinv[node];
    float2 xn = x2[node];
    float m0 = fmaf(s0, di, xn.x * di * di);
    float m1 = fmaf(s1, di, xn.y * di * di);
    float v = fmaf(m0, W1[lane], fmaf(m1, W1[HID + lane], b1[lane]));
    h1[(size_t)node * HID + lane] = fmaxf(v, 0.0f);
}

// ---------- hout = hin @ W (dense, W in LDS; 4 nodes/block) ----------
__global__ __launch_bounds__(256) void transform2_kernel(const float* __restrict__ hin,
                                                         const float* __restrict__ W,
                                                         float* __restrict__ hout, int N) {
    __shared__ float Ws[HID * HID];
    __shared__ float hs[4 * HID];
    for (int t = threadIdx.x; t < HID * HID; t += 256) Ws[t] = W[t];
    int ln = threadIdx.x >> 6;
    int j  = threadIdx.x & 63;
    int i  = blockIdx.x * 4 + ln;
    if (i < N) hs[ln * HID + j] = hin[(size_t)i * HID + j];
    __syncthreads();
    if (i >= N) return;
    float acc = 0.0f;
#pragma unroll
    for (int k = 0; k < HID; ++k)
        acc = fmaf(hs[ln * HID + k], Ws[k * HID + j], acc);
    hout[(size_t)i * HID + j] = acc;
}

// ---------- layer-2 gather + relu + mean-pool accumulate ----------
// cooperative index load + readlane broadcast + 4x unrolled independent row loads
__global__ void gather_pool_kernel(const int* __restrict__ rowptr, const int* __restrict__ esrc,
                                   const float* __restrict__ dinv, const float* __restrict__ h,
                                   const float* __restrict__ b, const int* __restrict__ batch,
                                   float* __restrict__ gsum, int* __restrict__ gcnt, int N) {
    int t = blockIdx.x * blockDim.x + threadIdx.x;
    int node = t >> 6, lane = t & 63;
    if (node >= N) return;
    int k0 = rowptr[node], k1 = rowptr[node + 1];
    float acc = 0.0f;
    for (int base = k0; base < k1; base += 64) {
        int cnt = min(64, k1 - base);
        int li = base + ((lane < cnt) ? lane : (cnt - 1));
        int sv = esrc[li];          // one coalesced load covers the whole chunk
        float dv = dinv[sv];        // parallel per-lane gather of weights
        int k = 0;
        for (; k + 4 <= cnt; k += 4) {
            int s0 = __builtin_amdgcn_readlane(sv, k);
            int s1 = __builtin_amdgcn_readlane(sv, k + 1);
            int s2 = __builtin_amdgcn_readlane(sv, k + 2);
            int s3 = __builtin_amdgcn_readlane(sv, k + 3);
            float w0 = bcast_f(dv, k);
            float w1 = bcast_f(dv, k + 1);
            float w2 = bcast_f(dv, k + 2);
            float w3 = bcast_f(dv, k + 3);
            float v0 = h[(size_t)s0 * HID + lane];   // 4 independent 256B row loads
            float v1 = h[(size_t)s1 * HID + lane];
            float v2 = h[(size_t)s2 * HID + lane];
            float v3 = h[(size_t)s3 * HID + lane];
            acc = fmaf(v0, w0, acc);
            acc = fmaf(v1, w1, acc);
            acc = fmaf(v2, w2, acc);
            acc = fmaf(v3, w3, acc);
        }
        for (; k < cnt; ++k) {
            int s = __builtin_amdgcn_readlane(sv, k);
            float w = bcast_f(dv, k);
            acc = fmaf(h[(size_t)s * HID + lane], w, acc);
        }
    }
    float di = dinv[node];
    float v = fmaf(acc, di, fmaf(h[(size_t)node * HID + lane], di * di, b[lane]));
    v = fmaxf(v, 0.0f);
    int g = batch[node];
    atomicAdd(&gsum[g * HID + lane], v);
    if (lane == 0) atomicAdd(&gcnt[g], 1);
}

// ---------- head ----------
__global__ void head_kernel(const float* __restrict__ gsum, const int* __restrict__ gcnt,
                            const float* __restrict__ Wf1, const float* __restrict__ bf1,
                            const float* __restrict__ Wf2, const float* __restrict__ bf2,
                            float* __restrict__ out) {
    __shared__ float gs[HID];
    __shared__ float ts[HID];
    int b = blockIdx.x;
    int j = threadIdx.x;
    float cnt = fmaxf((float)gcnt[b], 1.0f);
    gs[j] = gsum[b * HID + j] / cnt;
    __syncthreads();
    float acc = bf1[j];
#pragma unroll
    for (int k = 0; k < HID; ++k) acc = fmaf(gs[k], Wf1[k * HID + j], acc);
    ts[j] = fmaxf(acc, 0.0f);
    __syncthreads();
    if (j < 4) {
        float o = bf2[j];
#pragma unroll
        for (int k = 0; k < HID; ++k) o = fmaf(ts[k], Wf2[k * 4 + j], o);
        out[b * 4 + j] = o;
    }
}

extern "C" void kernel_launch(void* const* d_in, const int* in_sizes, int n_in,
                              void* d_out, int out_size, void* d_ws, size_t ws_size,
                              hipStream_t stream) {
    const float* x   = (const float*)d_in[0];
    const int*   ei  = (const int*)d_in[1];
    const int*   bat = (const int*)d_in[2];
    const float* W1  = (const float*)d_in[4];
    const float* b1  = (const float*)d_in[5];
    const float* W2  = (const float*)d_in[6];
    const float* b2  = (const float*)d_in[7];
    const float* Wf1 = (const float*)d_in[8];
    const float* bf1 = (const float*)d_in[9];
    const float* Wf2 = (const float*)d_in[10];
    const float* bf2 = (const float*)d_in[11];
    float* out = (float*)d_out;

    int N = in_sizes[2];
    int E = in_sizes[1] / 2;
    const int* src = ei;
    const int* dst = ei + E;
    int nb = (N + 255) / 256;

    char* ws = (char*)d_ws;
    size_t off = 0;
    auto alloc = [&](size_t bytes) {
        char* p = ws + off;
        off = (off + bytes + 255) & ~(size_t)255;
        return p;
    };
    int*   deg    = (int*)alloc((size_t)N * 4);
    float* dinv   = (float*)alloc((size_t)N * 4);
    int*   rowptr = (int*)alloc((size_t)(N + 1) * 4);
    int*   cur    = (int*)alloc((size_t)N * 4);
    int*   bsum   = (int*)alloc((size_t)nb * 4);
    int*   bofs   = (int*)alloc((size_t)nb * 4);
    int*   esrc   = (int*)alloc((size_t)E * 4);
    float* bufA   = (float*)alloc((size_t)N * HID * 4);
    float* bufB   = (float*)alloc((size_t)N * HID * 4);
    float* gsum   = (float*)alloc((size_t)NG * HID * 4);
    int*   gcnt   = (int*)alloc((size_t)NG * 4);

    hipMemsetAsync(deg, 0, (size_t)N * 4, stream);
    hipMemsetAsync(cur, 0, (size_t)N * 4, stream);
    hipMemsetAsync(gsum, 0, (size_t)NG * HID * 4, stream);
    hipMemsetAsync(gcnt, 0, (size_t)NG * 4, stream);

    int nh = N * HID;

    // degrees + normalization
    deg_kernel<<<(E + 255) / 256, 256, 0, stream>>>(dst, deg, E);
    dinv_kernel<<<(N + 255) / 256, 256, 0, stream>>>(deg, dinv, N);

    // CSR build (by dst)
    block_sums_kernel<<<nb, 256, 0, stream>>>(deg, bsum, N);
    scan_bsum_kernel<<<1, 64, 0, stream>>>(bsum, bofs, nb);
    scan_block_kernel<<<nb, 256, 0, stream>>>(deg, bofs, rowptr, N, E);
    bucket_kernel<<<(E + 255) / 256, 256, 0, stream>>>(src, dst, rowptr, cur, esrc, E);

    // layer 1 fused: bufB = h1 = relu((Ax)@W1 + b1)
    layer1_kernel<<<(nh + 255) / 256, 256, 0, stream>>>(x, rowptr, esrc, dinv, W1, b1, bufB, N);

    // layer 2: bufA = h1@W2; gather + relu + pool fused
    transform2_kernel<<<(N + 3) / 4, 256, 0, stream>>>(bufB, W2, bufA, N);
    gather_pool_kernel<<<(nh + 255) / 256, 256, 0, stream>>>(rowptr, esrc, dinv, bufA, b2, bat,
                                                            gsum, gcnt, N);

    // head
    head_kernel<<<NG, HID, 0, stream>>>(gsum, gcnt, Wf1, bf1, Wf2, bf2, out);
}